// Round 4
// baseline (2917.659 us; speedup 1.0000x reference)
//
#include <hip/hip_runtime.h>

// ---------------------------------------------------------------------------
// GRU (T=256, B=16, HID=1024, EMB=512, VOCAB=32000) + vocab projection.
//   prep_*  : cast weights/embeddings to bf16, split W into h-part / x-part
//   gemm_bt : C = A * B^T bf16 MFMA (Gx precompute only)
//   mega    : persistent 256-block kernel.
//     blocks 0..63  : GRU recurrence, weights LDS-resident.
//       - exchange (h_t, r*h) written UNCACHED (device-scope relaxed atomics
//         -> coherence point), slotted by timestep -> consumers read CACHED.
//       - sync = PER-WAVE producer flags (256 of them). Consumer wave wq only
//         needs K-range [256wq,256wq+256) = blocks 16wq..16wq+15, 4 waves
//         each -> its 64 lanes poll exactly those 64 flags. No grid barrier,
//         no producer-side block sync (wave-level vmcnt drain only).
//     blocks 64..255: work pool: items 0..499 convert Wd fp32->bf16
//       (uncached stores for cross-XCD visibility), items 500+ are projection
//       tiles gated on conv_done + the per-wave flags of the rows they need.
//       GRU blocks join the pool after the recurrence.
// ---------------------------------------------------------------------------

using bf16x8 = __attribute__((ext_vector_type(8))) __bf16;
using f32x4  = __attribute__((ext_vector_type(4))) float;

#define GRUB  64
#define TOTB  256
#define NTILE 250                   // 32000/128 col tiles
#define NGRP  32                    // 4096/128 row groups (8 timesteps each)
#define NCONV 500                   // Wd convert items (65536 floats each)
#define NITEM (NCONV + NGRP * NTILE)

__device__ __forceinline__ unsigned short f2bf(float f) {
  unsigned u = __builtin_bit_cast(unsigned, f);
  u += 0x7FFFu + ((u >> 16) & 1u);          // RNE
  return (unsigned short)(u >> 16);
}

__device__ __forceinline__ f32x4 mfma16(bf16x8 a, bf16x8 b, f32x4 c) {
  return __builtin_amdgcn_mfma_f32_16x16x32_bf16(a, b, c, 0, 0, 0);
}

__device__ __forceinline__ void ust32(unsigned* p, unsigned v) {
  __hip_atomic_store(p, v, __ATOMIC_RELAXED, __HIP_MEMORY_SCOPE_AGENT);
}
__device__ __forceinline__ void ust64(unsigned long long* p, unsigned long long v) {
  __hip_atomic_store(p, v, __ATOMIC_RELAXED, __HIP_MEMORY_SCOPE_AGENT);
}
__device__ __forceinline__ unsigned uld32(const unsigned* p) {
  return __hip_atomic_load(p, __ATOMIC_RELAXED, __HIP_MEMORY_SCOPE_AGENT);
}
__device__ __forceinline__ unsigned umin_(unsigned a, unsigned b) { return a < b ? a : b; }

// ---------------- prep kernels ----------------

__global__ void prep_w(const float* __restrict__ Wz, const float* __restrict__ Wr,
                       const float* __restrict__ Wm,
                       unsigned short* __restrict__ Whall,
                       unsigned short* __restrict__ Wxall) {
  int i = blockIdx.x * 256 + threadIdx.x;
  int g   = i / 393216;            // 1024*1536/4
  int rem = i % 393216;
  int j   = rem / 384;             // 1536/4
  int k   = (rem % 384) * 4;
  const float* src = (g == 0) ? Wz : (g == 1) ? Wr : Wm;
  float4 v = *(const float4*)(src + (size_t)j * 1536 + k);
  ushort4 o;
  o.x = f2bf(v.x); o.y = f2bf(v.y); o.z = f2bf(v.z); o.w = f2bf(v.w);
  if (k < 1024)
    *(ushort4*)(Whall + ((size_t)(g * 1024 + j) * 1024 + k)) = o;
  else
    *(ushort4*)(Wxall + ((size_t)(g * 1024 + j) * 512 + (k - 1024))) = o;
}

__global__ void prep_xe(const int* __restrict__ x, const float* __restrict__ emb,
                        unsigned short* __restrict__ xebf) {
  int i  = blockIdx.x * 256 + threadIdx.x;
  int tb = i >> 7, k = (i & 127) * 4;
  int tok = x[tb];
  float4 v = *(const float4*)(emb + (size_t)tok * 512 + k);
  ushort4 o;
  o.x = f2bf(v.x); o.y = f2bf(v.y); o.z = f2bf(v.z); o.w = f2bf(v.w);
  *(ushort4*)(xebf + (size_t)tb * 512 + k) = o;
}

__global__ void prep_h(const float* __restrict__ h, unsigned short* __restrict__ hbf) {
  int i = blockIdx.x * 256 + threadIdx.x;
  hbf[i] = f2bf(h[i]);
}

// ---------------- GEMM: C[M,N] = A[M,K] x B[N,K]^T (Gx precompute) ---------
__global__ __launch_bounds__(256) void gemm_bt(
    const unsigned short* __restrict__ A, const unsigned short* __restrict__ B,
    float* __restrict__ C, int M, int N, int K, int lda, int ldb, int ldc) {
  __shared__ uint4 As[128 * 5];
  __shared__ uint4 Bs[128 * 5];
  const int tid  = threadIdx.x;
  const int wid  = tid >> 6, lane = tid & 63;
  const int wr   = wid >> 1, wc = wid & 1;
  const int m0   = blockIdx.x * 128, n0 = blockIdx.y * 128;
  const int lr   = lane & 15, lk = lane >> 4;

  f32x4 acc[4][4] = {};
  const int nk = K >> 5;
  for (int kt = 0; kt < nk; ++kt) {
#pragma unroll
    for (int c = 0; c < 2; ++c) {
      int chunk = c * 256 + tid;
      int row = chunk >> 2, kc = chunk & 3;
      As[row * 5 + kc] = *(const uint4*)(A + (size_t)(m0 + row) * lda + kt * 32 + kc * 8);
      Bs[row * 5 + kc] = *(const uint4*)(B + (size_t)(n0 + row) * ldb + kt * 32 + kc * 8);
    }
    __syncthreads();
    bf16x8 af[4], bg[4];
#pragma unroll
    for (int i = 0; i < 4; ++i) {
      af[i] = __builtin_bit_cast(bf16x8, As[(wr * 64 + i * 16 + lr) * 5 + lk]);
      bg[i] = __builtin_bit_cast(bf16x8, Bs[(wc * 64 + i * 16 + lr) * 5 + lk]);
    }
#pragma unroll
    for (int i = 0; i < 4; ++i)
#pragma unroll
      for (int j = 0; j < 4; ++j)
        acc[i][j] = mfma16(af[i], bg[j], acc[i][j]);
    __syncthreads();
  }
#pragma unroll
  for (int i = 0; i < 4; ++i) {
    int mb = m0 + wr * 64 + i * 16 + lk * 4;
#pragma unroll
    for (int j = 0; j < 4; ++j) {
      int n = n0 + wc * 64 + j * 16 + lr;
#pragma unroll
      for (int q = 0; q < 4; ++q)
        C[(size_t)(mb + q) * ldc + n] = acc[i][j][q];
    }
  }
}

// ---------------- mega kernel ----------------
// flags layout (uints): [0..256) per-wave flags [bid*4+wq];
// [512] tile-queue counter; [544] conv_done.

__global__ __launch_bounds__(256, 1) void mega(
    const unsigned short* __restrict__ Whall, const float* __restrict__ Gx,
    const unsigned short* __restrict__ h0bf, const float* __restrict__ h0f,
    unsigned short* __restrict__ rhs, float* __restrict__ outh,
    unsigned short* __restrict__ allh,
    const float* __restrict__ Wd, unsigned short* __restrict__ Wdbf,
    float* __restrict__ outy, unsigned* __restrict__ flags) {
  __shared__ uint4 smem[6928];                 // 110,848 B -> 1 block/CU
  const int tid = threadIdx.x;
  const int bid = blockIdx.x;
  unsigned* ctrp  = flags + 512;
  unsigned* convp = flags + 544;

  if (bid < GRUB) {
    // ------------- GRU recurrence -------------
    uint4* Wl = smem;                                          // 6144 uint4
    float (*red)[4][16][16] = (float (*)[4][16][16])(smem + 6144); // 3 slots
    const int lane = tid & 63, wq = tid >> 6;
    const int c0   = bid * 16;
    const int lr   = lane & 15, lk = lane >> 4;
    const int bKu  = wq * 32;

    for (int it = 0; it < 24; ++it) {
      int chunk = it * 256 + tid;              // 0..6143
      int g = chunk >> 11, rem = chunk & 2047;
      int cl = rem >> 7, k8 = rem & 127;
      uint4 v = *(const uint4*)(Whall + ((size_t)(g * 1024 + c0 + cl) * 1024 + k8 * 8));
      Wl[(g * 16 + cl) * 128 + (k8 ^ (cl & 7))] = v;
    }

    const int b_  = tid >> 4, cl_ = tid & 15;
    const int cg  = c0 + cl_;
    unsigned* myflag = flags + (bid << 2) + wq;
    const unsigned* pollf = flags + (wq << 6) + lane;   // my 16 producers x 4 waves
    float hp = h0f[b_ * 1024 + cg];            // h lives in registers
    float zv = 0.f;
    __syncthreads();

    for (int t = 0; t < 256; ++t) {
      const size_t tb = (size_t)t * 16 + b_;
      float gz = Gx[tb * 3072 + cg];
      float gr = Gx[tb * 3072 + 1024 + cg];
      float gc = Gx[tb * 3072 + 2048 + cg];

      // ---- wait for h_{t-1} rows of my K-quarter (per-wave, 64 flags) ----
      if (t > 0) {
        while (uld32(pollf) < 2u * (unsigned)t) {}
      }
      asm volatile("" ::: "memory");

      // ---- phase 1: z, r ----
      const uint4* hp4 = (t == 0) ? (const uint4*)h0bf
                                  : (const uint4*)(allh + (size_t)(t - 1) * 16384);
      f32x4 az = {}, ar = {};
#pragma unroll
      for (int kk = 0; kk < 8; ++kk) {
        int ku = bKu + kk * 4 + lk;            // 0..127
        bf16x8 a  = __builtin_bit_cast(bf16x8, hp4[lr * 128 + ku]);
        bf16x8 bz = __builtin_bit_cast(bf16x8, Wl[(0 * 16 + lr) * 128 + (ku ^ (lr & 7))]);
        bf16x8 br = __builtin_bit_cast(bf16x8, Wl[(1 * 16 + lr) * 128 + (ku ^ (lr & 7))]);
        az = mfma16(a, bz, az);
        ar = mfma16(a, br, ar);
      }
#pragma unroll
      for (int q = 0; q < 4; ++q) {
        red[0][wq][lk * 4 + q][lr] = az[q];
        red[1][wq][lk * 4 + q][lr] = ar[q];
      }
      __syncthreads();
      {
        float sz = red[0][0][b_][cl_] + red[0][1][b_][cl_] + red[0][2][b_][cl_] +
                   red[0][3][b_][cl_] + gz;
        float sr = red[1][0][b_][cl_] + red[1][1][b_][cl_] + red[1][2][b_][cl_] +
                   red[1][3][b_][cl_] + gr;
        zv = 1.f / (1.f + __expf(-sz));
        float rv = 1.f / (1.f + __expf(-sr));
        unsigned short my = f2bf(rv * hp);
        unsigned other = __shfl_xor((unsigned)my, 1);
        if ((cl_ & 1) == 0)
          ust32((unsigned*)rhs + (((size_t)t * 16384 + b_ * 1024 + cg) >> 1),
                (unsigned)my | (other << 16));
      }
      asm volatile("s_waitcnt vmcnt(0)" ::: "memory");   // wave-level drain
      if (lane == 0) ust32(myflag, 2u * (unsigned)t + 1u);

      // ---- wait for rh rows of my K-quarter ----
      while (uld32(pollf) < 2u * (unsigned)t + 1u) {}
      asm volatile("" ::: "memory");

      // ---- phase 2: cand, h_new ----
      const uint4* rt4 = (const uint4*)(rhs + (size_t)t * 16384);
      f32x4 ac = {};
#pragma unroll
      for (int kk = 0; kk < 8; ++kk) {
        int ku = bKu + kk * 4 + lk;
        bf16x8 a  = __builtin_bit_cast(bf16x8, rt4[lr * 128 + ku]);
        bf16x8 bc = __builtin_bit_cast(bf16x8, Wl[(2 * 16 + lr) * 128 + (ku ^ (lr & 7))]);
        ac = mfma16(a, bc, ac);
      }
#pragma unroll
      for (int q = 0; q < 4; ++q) red[2][wq][lk * 4 + q][lr] = ac[q];
      __syncthreads();
      float hn;
      {
        float sc = red[2][0][b_][cl_] + red[2][1][b_][cl_] + red[2][2][b_][cl_] +
                   red[2][3][b_][cl_] + gc;
        float cand = tanhf(sc);
        hn = (1.f - zv) * hp + zv * cand;
        hp = hn;
        unsigned short my = f2bf(hn);
        unsigned other = __shfl_xor((unsigned)my, 1);
        if ((cl_ & 1) == 0)
          ust32((unsigned*)allh + (((size_t)t * 16384 + b_ * 1024 + cg) >> 1),
                (unsigned)my | (other << 16));
      }
      asm volatile("s_waitcnt vmcnt(0)" ::: "memory");
      if (lane == 0) ust32(myflag, 2u * (unsigned)t + 2u);
      outh[tb * 1024 + cg] = hn;               // off the critical path
    }
  }

  // ------------- work pool: Wd convert items, then projection tiles -------
  __syncthreads();
  uint4* As = smem;
  uint4* Bs = smem + 640;
  unsigned* wsh = (unsigned*)(smem + 6920);
  const int wid = tid >> 6, lane = tid & 63;
  const int wr = wid >> 1, wc = wid & 1;
  const int lr = lane & 15, lk = lane >> 4;

  for (;;) {
    __syncthreads();
    if (tid == 0)
      *wsh = __hip_atomic_fetch_add(ctrp, 1u, __ATOMIC_RELAXED,
                                    __HIP_MEMORY_SCOPE_AGENT);
    __syncthreads();
    unsigned w = *wsh;
    if (w >= (unsigned)NITEM) break;

    if (w < (unsigned)NCONV) {
      // convert 65536 floats of Wd -> Wdbf, UNCACHED 8B stores (visibility)
      const float4* src = (const float4*)Wd + (size_t)w * 16384;
      unsigned long long* dst = (unsigned long long*)Wdbf + (size_t)w * 16384;
      for (int it = 0; it < 64; ++it) {
        int idx = it * 256 + tid;
        float4 v = src[idx];
        ushort4 o;
        o.x = f2bf(v.x); o.y = f2bf(v.y); o.z = f2bf(v.z); o.w = f2bf(v.w);
        ust64(dst + idx, __builtin_bit_cast(unsigned long long, o));
      }
      asm volatile("s_waitcnt vmcnt(0)" ::: "memory");
      __syncthreads();
      if (tid == 0)
        __hip_atomic_fetch_add(convp, 1u, __ATOMIC_RELAXED,
                               __HIP_MEMORY_SCOPE_AGENT);
      continue;
    }

    unsigned p = w - NCONV;
    int g = p / NTILE, nt = p % NTILE;
    int m0 = g * 128, n0 = nt * 128;

    // gate: rows [m0,m0+128) done (all 256 wave flags >= 16g+16) + converts
    unsigned tgt = 16u * (unsigned)g + 16u;
    if (tid < 64) {
      const unsigned* f = flags + tid * 4;
      for (;;) {
        unsigned mn = umin_(umin_(uld32(f), uld32(f + 1)),
                            umin_(uld32(f + 2), uld32(f + 3)));
        if (mn >= tgt) break;
        __builtin_amdgcn_s_sleep(8);
      }
    }
    if (tid == 0)
      while (uld32(convp) < (unsigned)NCONV) __builtin_amdgcn_s_sleep(8);
    __syncthreads();

    f32x4 acc[4][4] = {};
    for (int kt = 0; kt < 32; ++kt) {
#pragma unroll
      for (int c = 0; c < 2; ++c) {
        int chunk = c * 256 + tid;
        int row = chunk >> 2, kc = chunk & 3;
        As[row * 5 + kc] = *(const uint4*)(allh + (size_t)(m0 + row) * 1024 + kt * 32 + kc * 8);
        Bs[row * 5 + kc] = *(const uint4*)(Wdbf + (size_t)(n0 + row) * 1024 + kt * 32 + kc * 8);
      }
      __syncthreads();
      bf16x8 af[4], bg[4];
#pragma unroll
      for (int i = 0; i < 4; ++i) {
        af[i] = __builtin_bit_cast(bf16x8, As[(wr * 64 + i * 16 + lr) * 5 + lk]);
        bg[i] = __builtin_bit_cast(bf16x8, Bs[(wc * 64 + i * 16 + lr) * 5 + lk]);
      }
#pragma unroll
      for (int i = 0; i < 4; ++i)
#pragma unroll
        for (int j = 0; j < 4; ++j)
          acc[i][j] = mfma16(af[i], bg[j], acc[i][j]);
      __syncthreads();
    }
#pragma unroll
    for (int i = 0; i < 4; ++i) {
      int mb = m0 + wr * 64 + i * 16 + lk * 4;
#pragma unroll
      for (int j = 0; j < 4; ++j) {
        int n = n0 + wc * 64 + j * 16 + lr;
#pragma unroll
        for (int q = 0; q < 4; ++q)
          outy[(size_t)(mb + q) * 32000 + n] = acc[i][j][q];
      }
    }
  }
}

// ---------------- workspace layout (bytes) ----------------
constexpr size_t OFF_WH  = 0;                                  // 6 MB
constexpr size_t OFF_WX  = OFF_WH + 3ull * 1024 * 1024 * 2;    // 3 MB
constexpr size_t OFF_WD  = OFF_WX + 3ull * 1024 * 512 * 2;     // 65.5 MB
constexpr size_t OFF_XE  = OFF_WD + 32000ull * 1024 * 2;       // 4.2 MB
constexpr size_t OFF_GX  = OFF_XE + 4096ull * 512 * 2;         // 50.3 MB
constexpr size_t OFF_AH  = OFF_GX + 4096ull * 3072 * 4;        // 8.4 MB
constexpr size_t OFF_H0  = OFF_AH + 4096ull * 1024 * 2;        // 32 KB
constexpr size_t OFF_RHS = OFF_H0 + 16384ull * 2;              // 8.4 MB
constexpr size_t OFF_FLG = OFF_RHS + 256ull * 16384 * 2;       // 16 KB

extern "C" void kernel_launch(void* const* d_in, const int* in_sizes, int n_in,
                              void* d_out, int out_size, void* d_ws, size_t ws_size,
                              hipStream_t stream) {
  const int*   x   = (const int*)d_in[0];
  const float* h0  = (const float*)d_in[1];
  const float* emb = (const float*)d_in[2];
  const float* Wz  = (const float*)d_in[3];
  const float* Wr  = (const float*)d_in[4];
  const float* Wm  = (const float*)d_in[5];
  const float* Wd  = (const float*)d_in[6];

  float* out_h = (float*)d_out;                        // [256*16, 1024]
  float* out_y = out_h + 4096ull * 1024;               // [256*16, 32000]

  char* ws = (char*)d_ws;
  unsigned short* Whall = (unsigned short*)(ws + OFF_WH);
  unsigned short* Wxall = (unsigned short*)(ws + OFF_WX);
  unsigned short* Wdbf  = (unsigned short*)(ws + OFF_WD);
  unsigned short* xebf  = (unsigned short*)(ws + OFF_XE);
  float*          Gx    = (float*)(ws + OFF_GX);
  unsigned short* allh  = (unsigned short*)(ws + OFF_AH);
  unsigned short* h0bf  = (unsigned short*)(ws + OFF_H0);
  unsigned short* rhs   = (unsigned short*)(ws + OFF_RHS);
  unsigned*       flags = (unsigned*)(ws + OFF_FLG);

  hipMemsetAsync(flags, 0, 16384, stream);

  prep_w <<<4608, 256, 0, stream>>>(Wz, Wr, Wm, Whall, Wxall);
  prep_xe<<<2048, 256, 0, stream>>>(x, emb, xebf);
  prep_h <<<64, 256, 0, stream>>>(h0, h0bf);

  // Gx[tb][g*1024+c] = xe[tb] . Wx_g[c]   (M=4096, N=3072, K=512)
  gemm_bt<<<dim3(32, 24), 256, 0, stream>>>(xebf, Wxall, Gx,
                                            4096, 3072, 512, 512, 512, 3072);

  mega<<<TOTB, 256, 0, stream>>>(Whall, Gx, h0bf, h0, rhs,
                                 out_h, allh, Wd, Wdbf, out_y, flags);
}

// Round 5
// 2004.825 us; speedup vs baseline: 1.4553x; 1.4553x over previous
//
#include <hip/hip_runtime.h>

// ---------------------------------------------------------------------------
// GRU (T=256, B=16, HID=1024, EMB=512, VOCAB=32000) + vocab projection.
//   prep_*  : cast weights/embeddings to bf16, split W into h-part / x-part
//   gemm_bt : C = A * B^T bf16 MFMA (Gx precompute only)
//   mega    : persistent 256-block kernel.
//     blocks 0..63  : GRU recurrence, weights LDS-resident.
//       - exchange (h_t, r*h) as TAGGED words (tag<<16 | bf16), uncached
//         fire-and-forget stores; consumers poll the DATA (self-validating,
//         spread over 64KB/slot -> no line contention, no flag round trip).
//       - per-block progress flags (128B stride) published lag-1 via LDS min;
//         only the projection pool polls them (with backoff).
//     blocks 64..255: work pool: items 0..499 convert Wd fp32->bf16
//       (uncached stores for cross-XCD visibility), items 500+ projection
//       tiles gated on conv_done + per-block flags. GRU blocks join after.
// ---------------------------------------------------------------------------

using bf16x8 = __attribute__((ext_vector_type(8))) __bf16;
using f32x4  = __attribute__((ext_vector_type(4))) float;

#define GRUB  64
#define TOTB  256
#define NTILE 250                   // 32000/128 col tiles
#define NGRP  32                    // 4096/128 row groups (8 timesteps each)
#define NCONV 500                   // Wd convert items (65536 floats each)
#define NITEM (NCONV + NGRP * NTILE)

__device__ __forceinline__ unsigned short f2bf(float f) {
  unsigned u = __builtin_bit_cast(unsigned, f);
  u += 0x7FFFu + ((u >> 16) & 1u);          // RNE
  return (unsigned short)(u >> 16);
}

__device__ __forceinline__ f32x4 mfma16(bf16x8 a, bf16x8 b, f32x4 c) {
  return __builtin_amdgcn_mfma_f32_16x16x32_bf16(a, b, c, 0, 0, 0);
}

__device__ __forceinline__ void ust32(unsigned* p, unsigned v) {
  __hip_atomic_store(p, v, __ATOMIC_RELAXED, __HIP_MEMORY_SCOPE_AGENT);
}
__device__ __forceinline__ void ust64(unsigned long long* p, unsigned long long v) {
  __hip_atomic_store(p, v, __ATOMIC_RELAXED, __HIP_MEMORY_SCOPE_AGENT);
}
__device__ __forceinline__ unsigned uld32(const unsigned* p) {
  return __hip_atomic_load(p, __ATOMIC_RELAXED, __HIP_MEMORY_SCOPE_AGENT);
}

// uncached (device-coherent) 16B load, issued WITHOUT waiting
#define ISSUE16(dst, p) \
  asm volatile("global_load_dwordx4 %0, %1, off sc0 sc1" : "=&v"(dst) : "v"(p))

// Poll one wave's K-quarter (8 fragments x 8 tagged words) until every word
// carries the expected tag; returns packed bf16x8 fragments. Loads are all
// in flight together; only stale fragments are re-issued.
__device__ __forceinline__ void poll_quarter(const unsigned* base, unsigned tgHi,
                                             bf16x8* af) {
  uint4 wa[8], wb[8];
  unsigned ok = 0;
  do {
#pragma unroll
    for (int kk = 0; kk < 8; ++kk)
      if (!(ok & (1u << kk))) {
        ISSUE16(wa[kk], base + kk * 32);
        ISSUE16(wb[kk], base + kk * 32 + 4);
      }
    asm volatile("s_waitcnt vmcnt(0)" ::: "memory");
    __builtin_amdgcn_sched_barrier(0);
#pragma unroll
    for (int kk = 0; kk < 8; ++kk)
      if (!(ok & (1u << kk))) {
        unsigned m = (wa[kk].x ^ tgHi) | (wa[kk].y ^ tgHi) |
                     (wa[kk].z ^ tgHi) | (wa[kk].w ^ tgHi) |
                     (wb[kk].x ^ tgHi) | (wb[kk].y ^ tgHi) |
                     (wb[kk].z ^ tgHi) | (wb[kk].w ^ tgHi);
        if (__all((int)(m >> 16) == 0)) ok |= 1u << kk;
      }
  } while (ok != 0xFFu);
#pragma unroll
  for (int kk = 0; kk < 8; ++kk) {
    uint4 r;
    r.x = __builtin_amdgcn_perm(wa[kk].y, wa[kk].x, 0x05040100);
    r.y = __builtin_amdgcn_perm(wa[kk].w, wa[kk].z, 0x05040100);
    r.z = __builtin_amdgcn_perm(wb[kk].y, wb[kk].x, 0x05040100);
    r.w = __builtin_amdgcn_perm(wb[kk].w, wb[kk].z, 0x05040100);
    af[kk] = __builtin_bit_cast(bf16x8, r);
  }
}

// ---------------- prep kernels ----------------

__global__ void prep_w(const float* __restrict__ Wz, const float* __restrict__ Wr,
                       const float* __restrict__ Wm,
                       unsigned short* __restrict__ Whall,
                       unsigned short* __restrict__ Wxall) {
  int i = blockIdx.x * 256 + threadIdx.x;
  int g   = i / 393216;            // 1024*1536/4
  int rem = i % 393216;
  int j   = rem / 384;             // 1536/4
  int k   = (rem % 384) * 4;
  const float* src = (g == 0) ? Wz : (g == 1) ? Wr : Wm;
  float4 v = *(const float4*)(src + (size_t)j * 1536 + k);
  ushort4 o;
  o.x = f2bf(v.x); o.y = f2bf(v.y); o.z = f2bf(v.z); o.w = f2bf(v.w);
  if (k < 1024)
    *(ushort4*)(Whall + ((size_t)(g * 1024 + j) * 1024 + k)) = o;
  else
    *(ushort4*)(Wxall + ((size_t)(g * 1024 + j) * 512 + (k - 1024))) = o;
}

__global__ void prep_xe(const int* __restrict__ x, const float* __restrict__ emb,
                        unsigned short* __restrict__ xebf) {
  int i  = blockIdx.x * 256 + threadIdx.x;
  int tb = i >> 7, k = (i & 127) * 4;
  int tok = x[tb];
  float4 v = *(const float4*)(emb + (size_t)tok * 512 + k);
  ushort4 o;
  o.x = f2bf(v.x); o.y = f2bf(v.y); o.z = f2bf(v.z); o.w = f2bf(v.w);
  *(ushort4*)(xebf + (size_t)tb * 512 + k) = o;
}

// write h0 into tagged slot 0 (tag = 1), uncached so mega's polls see it
__global__ void prep_h(const float* __restrict__ h, unsigned* __restrict__ HT) {
  int i = blockIdx.x * 256 + threadIdx.x;
  ust32(HT + i, (1u << 16) | (unsigned)f2bf(h[i]));
}

// ---------------- GEMM: C[M,N] = A[M,K] x B[N,K]^T (Gx precompute) ---------
__global__ __launch_bounds__(256) void gemm_bt(
    const unsigned short* __restrict__ A, const unsigned short* __restrict__ B,
    float* __restrict__ C, int M, int N, int K, int lda, int ldb, int ldc) {
  __shared__ uint4 As[128 * 5];
  __shared__ uint4 Bs[128 * 5];
  const int tid  = threadIdx.x;
  const int wid  = tid >> 6, lane = tid & 63;
  const int wr   = wid >> 1, wc = wid & 1;
  const int m0   = blockIdx.x * 128, n0 = blockIdx.y * 128;
  const int lr   = lane & 15, lk = lane >> 4;

  f32x4 acc[4][4] = {};
  const int nk = K >> 5;
  for (int kt = 0; kt < nk; ++kt) {
#pragma unroll
    for (int c = 0; c < 2; ++c) {
      int chunk = c * 256 + tid;
      int row = chunk >> 2, kc = chunk & 3;
      As[row * 5 + kc] = *(const uint4*)(A + (size_t)(m0 + row) * lda + kt * 32 + kc * 8);
      Bs[row * 5 + kc] = *(const uint4*)(B + (size_t)(n0 + row) * ldb + kt * 32 + kc * 8);
    }
    __syncthreads();
    bf16x8 af[4], bg[4];
#pragma unroll
    for (int i = 0; i < 4; ++i) {
      af[i] = __builtin_bit_cast(bf16x8, As[(wr * 64 + i * 16 + lr) * 5 + lk]);
      bg[i] = __builtin_bit_cast(bf16x8, Bs[(wc * 64 + i * 16 + lr) * 5 + lk]);
    }
#pragma unroll
    for (int i = 0; i < 4; ++i)
#pragma unroll
      for (int j = 0; j < 4; ++j)
        acc[i][j] = mfma16(af[i], bg[j], acc[i][j]);
    __syncthreads();
  }
#pragma unroll
  for (int i = 0; i < 4; ++i) {
    int mb = m0 + wr * 64 + i * 16 + lk * 4;
#pragma unroll
    for (int j = 0; j < 4; ++j) {
      int n = n0 + wc * 64 + j * 16 + lr;
#pragma unroll
      for (int q = 0; q < 4; ++q)
        C[(size_t)(mb + q) * ldc + n] = acc[i][j][q];
    }
  }
}

// ---------------- mega kernel ----------------
// flags (uints): [bid*32] per-block completed-steps; [2048] tile ctr;
// [2080] conv_done.

__global__ __launch_bounds__(256, 1) void mega(
    const unsigned short* __restrict__ Whall, const float* __restrict__ Gx,
    const float* __restrict__ h0f,
    unsigned* __restrict__ HT, unsigned* __restrict__ RT,
    float* __restrict__ outh, unsigned short* __restrict__ allh,
    const float* __restrict__ Wd, unsigned short* __restrict__ Wdbf,
    float* __restrict__ outy, unsigned* __restrict__ flags) {
  __shared__ uint4 smem[6928];                 // 110,848 B -> 1 block/CU
  const int tid = threadIdx.x;
  const int bid = blockIdx.x;
  unsigned* ctrp  = flags + 2048;
  unsigned* convp = flags + 2080;

  if (bid < GRUB) {
    // ------------- GRU recurrence -------------
    uint4* Wl = smem;                                          // 6144 uint4
    float (*red)[4][16][16] = (float (*)[4][16][16])(smem + 6144); // 3 slots
    volatile int* wave_done = (volatile int*)(smem + 6912);
    const int lane = tid & 63, wq = tid >> 6;
    const int c0   = bid * 16;
    const int lr   = lane & 15, lk = lane >> 4;
    const int bKu  = wq * 32;

    for (int it = 0; it < 24; ++it) {
      int chunk = it * 256 + tid;              // 0..6143
      int g = chunk >> 11, rem = chunk & 2047;
      int cl = rem >> 7, k8 = rem & 127;
      uint4 v = *(const uint4*)(Whall + ((size_t)(g * 1024 + c0 + cl) * 1024 + k8 * 8));
      Wl[(g * 16 + cl) * 128 + (k8 ^ (cl & 7))] = v;
    }
    if (tid < 4) wave_done[tid] = 0;

    const int b_  = tid >> 4, cl_ = tid & 15;
    const int cg  = c0 + cl_;
    unsigned* myflagp = flags + (bid << 5);
    // lane's first tagged word of its K-quarter
    const unsigned lane_off = (unsigned)(lr * 1024 + (bKu + lk) * 8);
    float hp = h0f[b_ * 1024 + cg];            // h lives in registers
    float zv = 0.f;
    __syncthreads();

    for (int t = 0; t < 256; ++t) {
      const size_t tb = (size_t)t * 16 + b_;
      float gz = Gx[tb * 3072 + cg];
      float gr = Gx[tb * 3072 + 1024 + cg];
      float gc = Gx[tb * 3072 + 2048 + cg];
      const unsigned tgHi = (unsigned)(t + 1) << 16;

      // ---- phase 1: z, r (poll tagged h slot t) ----
      bf16x8 af[8];
      poll_quarter(HT + (size_t)t * 16384 + lane_off, tgHi, af);

      // progress publish (my stores of steps < t are now drained)
      if (lane == 0) wave_done[wq] = t;
      if (tid == 0) {
        int m0_ = wave_done[0], m1 = wave_done[1];
        int m2 = wave_done[2], m3 = wave_done[3];
        int mn = min(min(m0_, m1), min(m2, m3));
        if (mn > 0) ust32(myflagp, (unsigned)mn);
      }

      f32x4 az = {}, ar = {};
#pragma unroll
      for (int kk = 0; kk < 8; ++kk) {
        int ku = bKu + kk * 4 + lk;            // 0..127
        bf16x8 bz = __builtin_bit_cast(bf16x8, Wl[(0 * 16 + lr) * 128 + (ku ^ (lr & 7))]);
        bf16x8 br = __builtin_bit_cast(bf16x8, Wl[(1 * 16 + lr) * 128 + (ku ^ (lr & 7))]);
        az = mfma16(af[kk], bz, az);
        ar = mfma16(af[kk], br, ar);
      }
#pragma unroll
      for (int q = 0; q < 4; ++q) {
        red[0][wq][lk * 4 + q][lr] = az[q];
        red[1][wq][lk * 4 + q][lr] = ar[q];
      }
      __syncthreads();
      {
        float sz = red[0][0][b_][cl_] + red[0][1][b_][cl_] + red[0][2][b_][cl_] +
                   red[0][3][b_][cl_] + gz;
        float sr = red[1][0][b_][cl_] + red[1][1][b_][cl_] + red[1][2][b_][cl_] +
                   red[1][3][b_][cl_] + gr;
        zv = 1.f / (1.f + __expf(-sz));
        float rv = 1.f / (1.f + __expf(-sr));
        // tagged r*h, fire and forget
        ust32(RT + (size_t)t * 16384 + b_ * 1024 + cg,
              tgHi | (unsigned)f2bf(rv * hp));
      }

      // ---- phase 2: cand, h_new (poll tagged rh slot t) ----
      poll_quarter(RT + (size_t)t * 16384 + lane_off, tgHi, af);
      f32x4 ac = {};
#pragma unroll
      for (int kk = 0; kk < 8; ++kk) {
        int ku = bKu + kk * 4 + lk;
        bf16x8 bc = __builtin_bit_cast(bf16x8, Wl[(2 * 16 + lr) * 128 + (ku ^ (lr & 7))]);
        ac = mfma16(af[kk], bc, ac);
      }
#pragma unroll
      for (int q = 0; q < 4; ++q) red[2][wq][lk * 4 + q][lr] = ac[q];
      __syncthreads();
      {
        float sc = red[2][0][b_][cl_] + red[2][1][b_][cl_] + red[2][2][b_][cl_] +
                   red[2][3][b_][cl_] + gc;
        float cand = tanhf(sc);
        float hn = (1.f - zv) * hp + zv * cand;
        hp = hn;
        unsigned short my = f2bf(hn);
        // tagged h for step t+1 consumers (slot t+1, tag t+2)
        ust32(HT + (size_t)(t + 1) * 16384 + b_ * 1024 + cg,
              ((unsigned)(t + 2) << 16) | (unsigned)my);
        // untagged bf16 for the projection (uncached for cross-XCD)
        unsigned other = __shfl_xor((unsigned)my, 1);
        if ((cl_ & 1) == 0)
          ust32((unsigned*)allh + (((size_t)t * 16384 + b_ * 1024 + cg) >> 1),
                (unsigned)my | (other << 16));
        outh[tb * 1024 + cg] = hn;             // plain cached, off crit path
      }
    }
    asm volatile("s_waitcnt vmcnt(0)" ::: "memory");
    __syncthreads();
    if (tid == 0) ust32(myflagp, 256u);
  }

  // ------------- work pool: Wd convert items, then projection tiles -------
  __syncthreads();
  uint4* As = smem;
  uint4* Bs = smem + 640;
  unsigned* wsh = (unsigned*)(smem + 6920);
  const int wid = tid >> 6, lane = tid & 63;
  const int wr = wid >> 1, wc = wid & 1;
  const int lr = lane & 15, lk = lane >> 4;

  for (;;) {
    __syncthreads();
    if (tid == 0)
      *wsh = __hip_atomic_fetch_add(ctrp, 1u, __ATOMIC_RELAXED,
                                    __HIP_MEMORY_SCOPE_AGENT);
    __syncthreads();
    unsigned w = *wsh;
    if (w >= (unsigned)NITEM) break;

    if (w < (unsigned)NCONV) {
      // convert 65536 floats of Wd -> Wdbf, UNCACHED 8B stores (visibility)
      const float4* src = (const float4*)Wd + (size_t)w * 16384;
      unsigned long long* dst = (unsigned long long*)Wdbf + (size_t)w * 16384;
      for (int it = 0; it < 64; ++it) {
        int idx = it * 256 + tid;
        float4 v = src[idx];
        ushort4 o;
        o.x = f2bf(v.x); o.y = f2bf(v.y); o.z = f2bf(v.z); o.w = f2bf(v.w);
        ust64(dst + idx, __builtin_bit_cast(unsigned long long, o));
      }
      asm volatile("s_waitcnt vmcnt(0)" ::: "memory");
      __syncthreads();
      if (tid == 0)
        __hip_atomic_fetch_add(convp, 1u, __ATOMIC_RELAXED,
                               __HIP_MEMORY_SCOPE_AGENT);
      continue;
    }

    unsigned p = w - NCONV;
    int g = p / NTILE, nt = p % NTILE;
    int m0 = g * 128, n0 = nt * 128;

    // gate: all 64 blocks past step 8g+8 (rows [m0,m0+128) drained) + convs
    unsigned tgt = 8u * (unsigned)g + 8u;
    if (tid < 64) {
      const unsigned* f = flags + tid * 32;
      while (uld32(f) < tgt) __builtin_amdgcn_s_sleep(8);
    }
    if (tid == 0)
      while (uld32(convp) < (unsigned)NCONV) __builtin_amdgcn_s_sleep(8);
    __syncthreads();

    f32x4 acc[4][4] = {};
    for (int kt = 0; kt < 32; ++kt) {
#pragma unroll
      for (int c = 0; c < 2; ++c) {
        int chunk = c * 256 + tid;
        int row = chunk >> 2, kc = chunk & 3;
        As[row * 5 + kc] = *(const uint4*)(allh + (size_t)(m0 + row) * 1024 + kt * 32 + kc * 8);
        Bs[row * 5 + kc] = *(const uint4*)(Wdbf + (size_t)(n0 + row) * 1024 + kt * 32 + kc * 8);
      }
      __syncthreads();
      bf16x8 af[4], bg[4];
#pragma unroll
      for (int i = 0; i < 4; ++i) {
        af[i] = __builtin_bit_cast(bf16x8, As[(wr * 64 + i * 16 + lr) * 5 + lk]);
        bg[i] = __builtin_bit_cast(bf16x8, Bs[(wc * 64 + i * 16 + lr) * 5 + lk]);
      }
#pragma unroll
      for (int i = 0; i < 4; ++i)
#pragma unroll
        for (int j = 0; j < 4; ++j)
          acc[i][j] = mfma16(af[i], bg[j], acc[i][j]);
      __syncthreads();
    }
#pragma unroll
    for (int i = 0; i < 4; ++i) {
      int mb = m0 + wr * 64 + i * 16 + lk * 4;
#pragma unroll
      for (int j = 0; j < 4; ++j) {
        int n = n0 + wc * 64 + j * 16 + lr;
#pragma unroll
        for (int q = 0; q < 4; ++q)
          outy[(size_t)(mb + q) * 32000 + n] = acc[i][j][q];
      }
    }
  }
}

// ---------------- workspace layout (bytes) ----------------
constexpr size_t OFF_WH  = 0;                                  // 6.3 MB
constexpr size_t OFF_WX  = OFF_WH + 3ull * 1024 * 1024 * 2;    // 3.1 MB
constexpr size_t OFF_WD  = OFF_WX + 3ull * 1024 * 512 * 2;     // 65.5 MB
constexpr size_t OFF_XE  = OFF_WD + 32000ull * 1024 * 2;       // 4.2 MB
constexpr size_t OFF_GX  = OFF_XE + 4096ull * 512 * 2;         // 50.3 MB
constexpr size_t OFF_AH  = OFF_GX + 4096ull * 3072 * 4;        // 8.4 MB
constexpr size_t OFF_HT  = OFF_AH + 4096ull * 1024 * 2;        // 16.9 MB tagged h
constexpr size_t OFF_RT  = OFF_HT + 257ull * 16384 * 4;        // 16.8 MB tagged rh
constexpr size_t OFF_FLG = OFF_RT + 256ull * 16384 * 4;        // 16 KB
constexpr size_t ZERO_SZ = OFF_FLG - OFF_HT;                   // HT+RT

extern "C" void kernel_launch(void* const* d_in, const int* in_sizes, int n_in,
                              void* d_out, int out_size, void* d_ws, size_t ws_size,
                              hipStream_t stream) {
  const int*   x   = (const int*)d_in[0];
  const float* h0  = (const float*)d_in[1];
  const float* emb = (const float*)d_in[2];
  const float* Wz  = (const float*)d_in[3];
  const float* Wr  = (const float*)d_in[4];
  const float* Wm  = (const float*)d_in[5];
  const float* Wd  = (const float*)d_in[6];

  float* out_h = (float*)d_out;                        // [256*16, 1024]
  float* out_y = out_h + 4096ull * 1024;               // [256*16, 32000]

  char* ws = (char*)d_ws;
  unsigned short* Whall = (unsigned short*)(ws + OFF_WH);
  unsigned short* Wxall = (unsigned short*)(ws + OFF_WX);
  unsigned short* Wdbf  = (unsigned short*)(ws + OFF_WD);
  unsigned short* xebf  = (unsigned short*)(ws + OFF_XE);
  float*          Gx    = (float*)(ws + OFF_GX);
  unsigned short* allh  = (unsigned short*)(ws + OFF_AH);
  unsigned*       HT    = (unsigned*)(ws + OFF_HT);
  unsigned*       RT    = (unsigned*)(ws + OFF_RT);
  unsigned*       flags = (unsigned*)(ws + OFF_FLG);

  // zero tags (graph replays re-run this, so stale tags never validate early)
  hipMemsetAsync(ws + OFF_HT, 0, ZERO_SZ, stream);
  hipMemsetAsync(flags, 0, 16384, stream);

  prep_w <<<4608, 256, 0, stream>>>(Wz, Wr, Wm, Whall, Wxall);
  prep_xe<<<2048, 256, 0, stream>>>(x, emb, xebf);
  prep_h <<<64, 256, 0, stream>>>(h0, HT);

  // Gx[tb][g*1024+c] = xe[tb] . Wx_g[c]   (M=4096, N=3072, K=512)
  gemm_bt<<<dim3(32, 24), 256, 0, stream>>>(xebf, Wxall, Gx,
                                            4096, 3072, 512, 512, 512, 3072);

  mega<<<TOTB, 256, 0, stream>>>(Whall, Gx, h0, HT, RT,
                                 out_h, allh, Wd, Wdbf, out_y, flags);
}